// Round 3
// baseline (1575.257 us; speedup 1.0000x reference)
//
#include <hip/hip_runtime.h>
#include <stdint.h>

#define S_DIM 8192
#define K_DIM 4096
#define N_DIM 4096

#define BM 128
#define BN 256
#define BKB 64               // bytes of K per stage (one 16x16x64 k-step)
#define NT (K_DIM / BKB)     // 64 stages

typedef int v4i __attribute__((ext_vector_type(4)));

// ---------------------------------------------------------------------------
// One launch: pack x (int32->int8), pack w, and copy scale_y to the output
// tail. Pack destination is contiguous in ws: [x packed | w packed].
__global__ void prep(const int* __restrict__ x, const int* __restrict__ w,
                     const float* __restrict__ sy,
                     int* __restrict__ dst, float* __restrict__ out) {
    const int nx = S_DIM * K_DIM / 4;
    const int nw = N_DIM * K_DIM / 4;
    int i = blockIdx.x * 256 + threadIdx.x;
    if (i < nx) {
        int4 a = ((const int4*)x)[i];
        dst[i] = (a.x & 0xFF) | ((a.y & 0xFF) << 8) | ((a.z & 0xFF) << 16)
               | ((a.w & 0xFF) << 24);
    } else if (i < nx + nw) {
        int4 a = ((const int4*)w)[i - nx];
        dst[i] = (a.x & 0xFF) | ((a.y & 0xFF) << 8) | ((a.z & 0xFF) << 16)
               | ((a.w & 0xFF) << 24);
    } else {
        int j = i - nx - nw;
        if (j < S_DIM) out[(size_t)S_DIM * N_DIM + j] = sy[j];
    }
}

// scale_y tail only (used by the no-workspace fallback path)
__global__ void copy_sy(const float* __restrict__ sy, float* __restrict__ out) {
    int i = blockIdx.x * blockDim.x + threadIdx.x;
    if (i < S_DIM) out[(size_t)S_DIM * N_DIM + i] = sy[i];
}

// ---------------------------------------------------------------------------
__device__ __forceinline__ void g2lds16(const void* g, void* l) {
    __builtin_amdgcn_global_load_lds((const __attribute__((address_space(1))) void*)g,
                                     (__attribute__((address_space(3))) void*)l,
                                     16, 0, 0);
}

// ---------------------------------------------------------------------------
// 128x256 tile i8 MFMA GEMM. 4 waves 2x2, each wave 64m x 128n = 4x8 tiles of
// mfma_i32_16x16x64_i8. Schedule is the proven R0 form: stage -> syncthreads
// (vmcnt0 drain) -> frag reads -> MFMA, compiler-scheduled, NO sched_barrier /
// counted-vmcnt / setprio (R1/R2 showed all of those regress this kernel;
// m141 measured sched_barrier(0) pinning at -42%).
//
// R3 change: BKB 128 -> 64, single-buffered => LDS = 24 KB/block => FOUR
// blocks/CU resident (R0 ran 2; both pipes sat at ~50% from serialization).
// Grid = 1024 = exactly 4 blocks x 256 CUs: the whole grid is co-resident,
// and each block's barrier/drain bubbles are covered by the other three
// blocks' MFMA phases. VGPR=108 <= 128 keeps 16 waves/CU legal.
//
// LDS swizzle (refcheck'd absmax=0 + 0 bank conflicts in R2): 64-B rows;
// pairs of rows form 128-B super-rows of 8 16B chunks; chunk p of super-row s
// lives at slot p ^ (s&7). A wave's fragment ds_read_b128 touches each
// super-row's 8 slots as a full permutation -> all 32 banks once per
// super-row, 2 lanes/bank = conflict-free. global_load_lds writes LDS
// linearly with the INVERSE permutation applied to the per-lane global source
// address (both-sides-or-neither rule).
__launch_bounds__(256, 4)
__global__ void gemm_i8(const signed char* __restrict__ xp,
                        const signed char* __restrict__ wp,
                        const float* __restrict__ sx,
                        const float* __restrict__ sw,
                        const float* __restrict__ sy,
                        float* __restrict__ out) {
    __shared__ __align__(16) signed char As[BM * BKB];   // 8 KB
    __shared__ __align__(16) signed char Bs[BN * BKB];   // 16 KB

    const int tid  = threadIdx.x;
    const int lane = tid & 63;
    const int quad = lane >> 4;    // 16B k-chunk within the 64B k-step
    const int l16  = lane & 15;    // row (A) / col (B) within 16
    const int wave = tid >> 6;     // 0..3
    const int wm = wave >> 1;      // 64-row slab
    const int wn = wave & 1;       // 128-col slab
    const int bn = blockIdx.x;     // fast axis
    const int bm = blockIdx.y;

    const signed char* aG = xp + (size_t)(bm * BM) * K_DIM;
    const signed char* bG = wp + (size_t)(bn * BN) * K_DIM;

    // Staging source offsets. Per stage: A = 512 chunks (2/thread),
    // B = 1024 chunks (4/thread). LDS chunk L: super-row s=L>>3, slot=L&7,
    // global chunk p = slot^(s&7) -> row = 2s+(p>>2), kchunk = p&3.
    int aOff[2], bOff[4];
#pragma unroll
    for (int i = 0; i < 2; i++) {
        int L = i * 256 + tid;
        int s = L >> 3, p = (L & 7) ^ (s & 7);
        aOff[i] = (2 * s + (p >> 2)) * K_DIM + ((p & 3) << 4);
    }
#pragma unroll
    for (int i = 0; i < 4; i++) {
        int L = i * 256 + tid;
        int s = L >> 3, p = (L & 7) ^ (s & 7);
        bOff[i] = (2 * s + (p >> 2)) * K_DIM + ((p & 3) << 4);
    }

    // Fragment read offset for (row = base16 + l16, chunk = quad):
    // byte = base16*64 + (l16>>1)*128 + ((((l16&1)<<2)|quad)^(l16>>1))*16.
    const int rdo = ((l16 >> 1) * 128)
                  + (((((l16 & 1) << 2) | quad) ^ (l16 >> 1)) << 4);

    v4i acc[4][8];
#pragma unroll
    for (int i = 0; i < 4; i++)
#pragma unroll
        for (int j = 0; j < 8; j++) acc[i][j] = 0;

    const signed char* a_lds = As + wm * 4096 + rdo;
    const signed char* b_lds = Bs + wn * 8192 + rdo;

    for (int t = 0; t < NT; ++t) {
        const int kk = t * BKB;
        __syncthreads();  // previous stage's readers done -> LDS reusable
        g2lds16(aG + aOff[0] + kk, As + tid * 16);
        g2lds16(aG + aOff[1] + kk, As + 4096 + tid * 16);
        g2lds16(bG + bOff[0] + kk, Bs + tid * 16);
        g2lds16(bG + bOff[1] + kk, Bs + 4096 + tid * 16);
        g2lds16(bG + bOff[2] + kk, Bs + 8192 + tid * 16);
        g2lds16(bG + bOff[3] + kk, Bs + 12288 + tid * 16);
        __syncthreads();  // vmcnt(0) drain: stage complete

        v4i af[4], bf[8];
#pragma unroll
        for (int mt = 0; mt < 4; mt++)
            af[mt] = *(const v4i*)(a_lds + mt * 1024);
#pragma unroll
        for (int nt = 0; nt < 8; nt++)
            bf[nt] = *(const v4i*)(b_lds + nt * 1024);
#pragma unroll
        for (int mt = 0; mt < 4; mt++)
#pragma unroll
            for (int nt = 0; nt < 8; nt++)
                acc[mt][nt] = __builtin_amdgcn_mfma_i32_16x16x64_i8(
                    af[mt], bf[nt], acc[mt][nt], 0, 0, 0);
    }

    // Epilogue: C/D layout: col = lane&15, row = quad*4 + reg.
    const int s_base = bm * BM + wm * 64;
    const int n_base = bn * BN + wn * 128;
#pragma unroll
    for (int mt = 0; mt < 4; mt++) {
#pragma unroll
        for (int r = 0; r < 4; r++) {
            int s = s_base + mt * 16 + quad * 4 + r;
            float rs = sx[s] / sy[s];
            float* orow = out + (size_t)s * N_DIM;
#pragma unroll
            for (int nt = 0; nt < 8; nt++) {
                int n = n_base + nt * 16 + l16;
                float v = rintf((float)acc[mt][nt][r] * (rs * sw[n]));
                v = fminf(fmaxf(v, -128.f), 127.f);
                orow[n] = v;
            }
        }
    }
}

// ---------------------------------------------------------------------------
// Correctness fallback if the workspace is too small for packed operands.
__global__ void gemm_naive(const int* __restrict__ x, const int* __restrict__ w,
                           const float* __restrict__ sx, const float* __restrict__ sw,
                           const float* __restrict__ sy, float* __restrict__ out) {
    int n = blockIdx.x * blockDim.x + threadIdx.x;
    int s = blockIdx.y;
    const int4* xr = (const int4*)(x + (size_t)s * K_DIM);
    const int4* wr = (const int4*)(w + (size_t)n * K_DIM);
    int acc = 0;
    for (int k = 0; k < K_DIM / 4; k++) {
        int4 a = xr[k], b = wr[k];
        acc += a.x * b.x + a.y * b.y + a.z * b.z + a.w * b.w;
    }
    float v = rintf((float)acc * (sx[s] / sy[s] * sw[n]));
    out[(size_t)s * N_DIM + n] = fminf(fmaxf(v, -128.f), 127.f);
}

// ---------------------------------------------------------------------------
extern "C" void kernel_launch(void* const* d_in, const int* in_sizes, int n_in,
                              void* d_out, int out_size, void* d_ws, size_t ws_size,
                              hipStream_t stream) {
    const int*   x  = (const int*)d_in[0];     // [S, K] int8 values widened to int32
    const int*   wq = (const int*)d_in[1];     // [N, K]
    const float* sx = (const float*)d_in[2];   // [S]
    const float* sw = (const float*)d_in[3];   // [N]
    const float* sy = (const float*)d_in[4];   // [S]
    float* out = (float*)d_out;                // [S*N out_q] ++ [S scale_y], float32

    const size_t need = (size_t)S_DIM * K_DIM + (size_t)N_DIM * K_DIM;  // 48 MiB
    if (ws_size >= need) {
        signed char* xp = (signed char*)d_ws;
        signed char* wp = xp + (size_t)S_DIM * K_DIM;
        const int nprep = (S_DIM * K_DIM / 4) + (N_DIM * K_DIM / 4) + S_DIM;
        prep<<<dim3((nprep + 255) / 256), dim3(256), 0, stream>>>(
            x, wq, sy, (int*)xp, out);
        gemm_i8<<<dim3(N_DIM / BN, S_DIM / BM), dim3(256), 0, stream>>>(
            xp, wp, sx, sw, sy, out);
    } else {
        copy_sy<<<dim3((S_DIM + 255) / 256), dim3(256), 0, stream>>>(sy, out);
        gemm_naive<<<dim3(N_DIM / 256, S_DIM), dim3(256), 0, stream>>>(
            x, wq, sx, sw, sy, out);
    }
}

// Round 4
// 378.456 us; speedup vs baseline: 4.1623x; 4.1623x over previous
//
#include <hip/hip_runtime.h>
#include <stdint.h>

#define S_DIM 8192
#define K_DIM 4096
#define N_DIM 4096

#define BM 128
#define BN 256
#define BK 128   // bytes of K per staging stage (2 MFMA k-steps of 64)

typedef int v4i __attribute__((ext_vector_type(4)));

// ---------------------------------------------------------------------------
// One launch: pack x (int32->int8), pack w, and copy scale_y to the output
// tail. Pack destination is contiguous in ws: [x packed | w packed].
__global__ void prep(const int* __restrict__ x, const int* __restrict__ w,
                     const float* __restrict__ sy,
                     int* __restrict__ dst, float* __restrict__ out) {
    const int nx = S_DIM * K_DIM / 4;
    const int nw = N_DIM * K_DIM / 4;
    int i = blockIdx.x * 256 + threadIdx.x;
    if (i < nx) {
        int4 a = ((const int4*)x)[i];
        dst[i] = (a.x & 0xFF) | ((a.y & 0xFF) << 8) | ((a.z & 0xFF) << 16)
               | ((a.w & 0xFF) << 24);
    } else if (i < nx + nw) {
        int4 a = ((const int4*)w)[i - nx];
        dst[i] = (a.x & 0xFF) | ((a.y & 0xFF) << 8) | ((a.z & 0xFF) << 16)
               | ((a.w & 0xFF) << 24);
    } else {
        int j = i - nx - nw;
        if (j < S_DIM) out[(size_t)S_DIM * N_DIM + j] = sy[j];
    }
}

// scale_y tail only (used by the no-workspace fallback path)
__global__ void copy_sy(const float* __restrict__ sy, float* __restrict__ out) {
    int i = blockIdx.x * blockDim.x + threadIdx.x;
    if (i < S_DIM) out[(size_t)S_DIM * N_DIM + i] = sy[i];
}

// ---------------------------------------------------------------------------
__device__ __forceinline__ void g2lds16(const void* g, void* l) {
    __builtin_amdgcn_global_load_lds((const __attribute__((address_space(1))) void*)g,
                                     (__attribute__((address_space(3))) void*)l,
                                     16, 0, 0);
}

// ---------------------------------------------------------------------------
// 128x256 tile i8 MFMA GEMM — byte-identical to the proven 131-us R0 kernel
// (4 waves 2x2, each wave 64m x 128n as 4x8 tiles of mfma_i32_16x16x64_i8,
// global_load_lds staging, XOR-swizzled LDS, 2 blocks/CU) EXCEPT the compute
// region: both k-steps' fragments are read up front (ks0 then ks1, distinct
// names), then both MFMA clusters. R0's per-kstep read->MFMA alternation
// fully serialized the LDS pipe (61 us) with the matrix pipe (70 us):
// 61+70 = the measured 131 us. The ks1 reads are independent of the ks0
// MFMAs, so the compiler's counted lgkmcnt can drain them under the first
// 32 MFMAs. Peak liveness ~250 regs (acc 128 + frags 96 + addr ~26) stays
// under the 256-reg 2-waves/SIMD wall (R3 measured what crossing it costs:
// accumulator spill, 6.7 GB scratch traffic, 10x slowdown).
//
// Occupancy/launch structure deliberately unchanged (R1: 1 block/CU = -17%;
// R2: sched_barrier/counted-vmcnt ring = -26%; R3: 4 blocks/CU = spill).
__launch_bounds__(256, 2)
__global__ void gemm_i8(const signed char* __restrict__ xp,
                        const signed char* __restrict__ wp,
                        const float* __restrict__ sx,
                        const float* __restrict__ sw,
                        const float* __restrict__ sy,
                        float* __restrict__ out) {
    __shared__ __align__(16) signed char As[BM * BK];   // 16 KB
    __shared__ __align__(16) signed char Bs[BN * BK];   // 32 KB

    const int tid  = threadIdx.x;
    const int lane = tid & 63;
    const int quad = lane >> 4;    // 0..3 -> 16B k-chunk within a 64B k-step
    const int l16  = lane & 15;    // row (A) / col (B) within 16
    const int wave = tid >> 6;     // 0..3
    const int wm = wave >> 1;      // wave m (2): 64-row slab
    const int wn = wave & 1;       // wave n (2): 128-col slab
    const int bn = blockIdx.x;     // fast axis
    const int bm = blockIdx.y;

    const signed char* aG = xp + (size_t)(bm * BM) * K_DIM;
    const signed char* bG = wp + (size_t)(bn * BN) * K_DIM;

    const int csw = l16 & 7;       // fragment-read swizzle component

    // Hoisted per-thread staging offsets (loop-invariant): A = 1024 chunks,
    // B = 2048 chunks of 16B; thread handles 4 A + 8 B chunks per stage.
    int aOff[4], bOff[8];
#pragma unroll
    for (int i = 0; i < 4; i++) {
        int li = i * 256 + tid;
        int row = li >> 3, c = li & 7, g = c ^ (row & 7);
        aOff[i] = row * K_DIM + (g << 4);
    }
#pragma unroll
    for (int i = 0; i < 8; i++) {
        int li = i * 256 + tid;
        int row = li >> 3, c = li & 7, g = c ^ (row & 7);
        bOff[i] = row * K_DIM + (g << 4);
    }

    v4i acc[4][8];
#pragma unroll
    for (int i = 0; i < 4; i++)
#pragma unroll
        for (int j = 0; j < 8; j++) acc[i][j] = 0;

    const int slot0 = (0 | quad) ^ csw;            // ks=0 swizzled k-chunk
    const int slot1 = (4 | quad) ^ csw;            // ks=1 swizzled k-chunk
    const signed char* aBase = As + (wm * 64 + l16) * BK;
    const signed char* bBase = Bs + (wn * 128 + l16) * BK;

    for (int kk = 0; kk < K_DIM; kk += BK) {
        __syncthreads();  // protect LDS from previous iteration's readers
#pragma unroll
        for (int i = 0; i < 4; i++)
            g2lds16(aG + aOff[i] + kk, As + (i * 256 + tid) * 16);
#pragma unroll
        for (int i = 0; i < 8; i++)
            g2lds16(bG + bOff[i] + kk, Bs + (i * 256 + tid) * 16);
        __syncthreads();  // vmcnt(0) drain: staging complete

        // --- read BOTH k-steps' fragments up front; ks1's reads drain
        // --- under the ks0 MFMA cluster (independent, counted lgkmcnt).
        v4i af0[4], bf0[8], af1[4], bf1[8];
#pragma unroll
        for (int t = 0; t < 4; t++)
            af0[t] = *(const v4i*)(aBase + t * (16 * BK) + (slot0 << 4));
#pragma unroll
        for (int u = 0; u < 8; u++)
            bf0[u] = *(const v4i*)(bBase + u * (16 * BK) + (slot0 << 4));
#pragma unroll
        for (int t = 0; t < 4; t++)
            af1[t] = *(const v4i*)(aBase + t * (16 * BK) + (slot1 << 4));
#pragma unroll
        for (int u = 0; u < 8; u++)
            bf1[u] = *(const v4i*)(bBase + u * (16 * BK) + (slot1 << 4));

#pragma unroll
        for (int mt = 0; mt < 4; mt++)
#pragma unroll
            for (int nt = 0; nt < 8; nt++)
                acc[mt][nt] = __builtin_amdgcn_mfma_i32_16x16x64_i8(
                    af0[mt], bf0[nt], acc[mt][nt], 0, 0, 0);
#pragma unroll
        for (int mt = 0; mt < 4; mt++)
#pragma unroll
            for (int nt = 0; nt < 8; nt++)
                acc[mt][nt] = __builtin_amdgcn_mfma_i32_16x16x64_i8(
                    af1[mt], bf1[nt], acc[mt][nt], 0, 0, 0);
    }

    // Epilogue: C/D layout: col = lane&15, row = quad*4 + reg.
    const int s_base = bm * BM + wm * 64;
    const int n_base = bn * BN + wn * 128;
#pragma unroll
    for (int mt = 0; mt < 4; mt++) {
#pragma unroll
        for (int r = 0; r < 4; r++) {
            int s = s_base + mt * 16 + quad * 4 + r;
            float rs = sx[s] / sy[s];
            float* orow = out + (size_t)s * N_DIM;
#pragma unroll
            for (int nt = 0; nt < 8; nt++) {
                int n = n_base + nt * 16 + l16;
                float v = rintf((float)acc[mt][nt][r] * (rs * sw[n]));
                v = fminf(fmaxf(v, -128.f), 127.f);
                orow[n] = v;
            }
        }
    }
}

// ---------------------------------------------------------------------------
// Correctness fallback if the workspace is too small for packed operands.
__global__ void gemm_naive(const int* __restrict__ x, const int* __restrict__ w,
                           const float* __restrict__ sx, const float* __restrict__ sw,
                           const float* __restrict__ sy, float* __restrict__ out) {
    int n = blockIdx.x * blockDim.x + threadIdx.x;
    int s = blockIdx.y;
    const int4* xr = (const int4*)(x + (size_t)s * K_DIM);
    const int4* wr = (const int4*)(w + (size_t)n * K_DIM);
    int acc = 0;
    for (int k = 0; k < K_DIM / 4; k++) {
        int4 a = xr[k], b = wr[k];
        acc += a.x * b.x + a.y * b.y + a.z * b.z + a.w * b.w;
    }
    float v = rintf((float)acc * (sx[s] / sy[s] * sw[n]));
    out[(size_t)s * N_DIM + n] = fminf(fmaxf(v, -128.f), 127.f);
}

// ---------------------------------------------------------------------------
extern "C" void kernel_launch(void* const* d_in, const int* in_sizes, int n_in,
                              void* d_out, int out_size, void* d_ws, size_t ws_size,
                              hipStream_t stream) {
    const int*   x  = (const int*)d_in[0];     // [S, K] int8 values widened to int32
    const int*   wq = (const int*)d_in[1];     // [N, K]
    const float* sx = (const float*)d_in[2];   // [S]
    const float* sw = (const float*)d_in[3];   // [N]
    const float* sy = (const float*)d_in[4];   // [S]
    float* out = (float*)d_out;                // [S*N out_q] ++ [S scale_y], float32

    const size_t need = (size_t)S_DIM * K_DIM + (size_t)N_DIM * K_DIM;  // 48 MiB
    if (ws_size >= need) {
        signed char* xp = (signed char*)d_ws;
        signed char* wp = xp + (size_t)S_DIM * K_DIM;
        const int nprep = (S_DIM * K_DIM / 4) + (N_DIM * K_DIM / 4) + S_DIM;
        prep<<<dim3((nprep + 255) / 256), dim3(256), 0, stream>>>(
            x, wq, sy, (int*)xp, out);
        gemm_i8<<<dim3(N_DIM / BN, S_DIM / BM), dim3(256), 0, stream>>>(
            xp, wp, sx, sw, sy, out);
    } else {
        copy_sy<<<dim3((S_DIM + 255) / 256), dim3(256), 0, stream>>>(sy, out);
        gemm_naive<<<dim3(N_DIM / 256, S_DIM), dim3(256), 0, stream>>>(
            x, wq, sx, sw, sy, out);
    }
}